// Round 11
// baseline (118.534 us; speedup 1.0000x reference)
//
// NeuralExecutor2 — r11: latency attack. TI=2 (1024 blocks, 50% occupancy),
// unroll-16 scan (wide vmcnt groups), all epilogue weights/operands staged
// into LDS during phase 0 (no serialized global loads after the scan).
#include <hip/hip_runtime.h>

#define XN 512
#define XB 4
#define XNEG  (-3.402823466e38f)  // -FLT_MAX: max-reduction init
#define XMASK (-1.0e38f)          // additive fold for masked entries (finite)

__device__ __forceinline__ float xscrub(float v) {
    unsigned u = __float_as_uint(v);
    u = ((u & 0x7f800000u) == 0x7f800000u) ? 0xff7fffffu : u;  // inf/nan -> -FLT_MAX bits
    return __uint_as_float(u);
}

// ---- g0: derived vectors (c1,c2,u1,u2,cp) + tau zero ----
__global__ __launch_bounds__(64) void ne2v_g0(
    const float* __restrict__ We, const float* __restrict__ Wm,
    const float* __restrict__ Wtm, const float* __restrict__ Wtu,
    const float* __restrict__ Wt, const float* __restrict__ Wp,
    float* __restrict__ drv, float* __restrict__ tau_out)
{
    const int t = threadIdx.x;
    if (t < 32) {
        float c1 = 0.f, c2 = 0.f;
        for (int k = 0; k < 32; ++k) {
            const float w = We[k];
            c1 += w * Wm[(64 + k) * 32 + t];
            c2 += w * Wtm[(64 + k) * 32 + t];
        }
        drv[t]      = c1;
        drv[32 + t] = c2;
        float u1 = 0.f, u2 = 0.f;
        for (int k = 0; k < 32; ++k) {
            u1 += Wtu[t * 32 + k]        * Wt[k];
            u2 += Wtu[(32 + t) * 32 + k] * Wt[k];
        }
        drv[64 + t] = u1;
        drv[96 + t] = u2;
        if (t == 0) {
            float cp = 0.f;
            for (int k = 0; k < 32; ++k) cp += We[k] * Wp[64 + k];
            drv[128] = cp;
        }
    }
    if (t < XB) tau_out[t] = 0.f;
}

// ---- g1: z = [x,h]@Wn ; A1 = z@Wm[0:32] ; B1 = z@Wm[32:64] ----
__global__ __launch_bounds__(256) void ne2v_g1(
    const float* __restrict__ x, const float* __restrict__ h,
    const float* __restrict__ Wn, const float* __restrict__ Wm,
    float* __restrict__ z, float* __restrict__ A1, float* __restrict__ B1)
{
    const int t = threadIdx.x;
    const int r = t >> 5;
    const int l = t & 31;
    const int row = blockIdx.x * 8 + r;
    float acc = 0.f;
    {
        const float* xr = x + row * 3;
        const float* hr = h + row * 32;
        for (int k = 0; k < 3; ++k)  acc += xr[k] * Wn[k * 32 + l];
        for (int k = 0; k < 32; ++k) acc += hr[k] * Wn[(3 + k) * 32 + l];
    }
    __shared__ float zs[8][32];
    zs[r][l] = acc;
    z[row * 32 + l] = acc;
    __syncthreads();
    float a = 0.f, bb = 0.f;
    for (int k = 0; k < 32; ++k) {
        const float zk = zs[r][k];
        a  += zk * Wm[k * 32 + l];
        bb += zk * Wm[(32 + k) * 32 + l];
    }
    A1[row * 32 + l] = a;
    B1[row * 32 + l] = bb;
}

// ---- m2: mpnn1 — 2 rows/block, 1024 blocks ----
__global__ __launch_bounds__(256) void ne2v_m2(
    const int* __restrict__ adj, const float* __restrict__ ef,
    const float* __restrict__ z, const float* __restrict__ A1,
    const float* __restrict__ B1, const float* __restrict__ drv,
    const float* __restrict__ Wu, const float* __restrict__ Wd,
    const float* __restrict__ Wtm, const float* __restrict__ Wp,
    float* __restrict__ A2, float* __restrict__ B2,
    float* __restrict__ hp1, float* __restrict__ hp2,
    float* __restrict__ o_newx, float* __restrict__ o_newh)
{
    const int q = blockIdx.x;                 // 0..1023
    const int b = q >> 8;                     // 256 blocks per batch
    const int i0 = (q & 255) * 2;
    const int row0 = b * XN + i0;
    const int t = threadIdx.x;

    __shared__ float emf[2 * XN];             // [j*2+r] e or 0
    __shared__ float adf[2 * XN];             // [j*2+r] 0 or -1e38
    __shared__ float wush[64 * 32];           // Wu
    __shared__ float wtmsh[64 * 32];          // Wtm
    __shared__ float wdsh[192];               // Wd (64x3)
    __shared__ float wpsh[64];                // Wp[0:64]
    __shared__ float zsf[64], a1sf[64], ags[64], nhs[64];
    __shared__ float red[2][8][33];

    // ---- phase 0: all staging loads issued together ----
    const float c1v = drv[t & 31];            // per-lane scan constant
    {
        const int*   ab = adj + (size_t)row0 * XN;
        const float* eb = ef  + (size_t)row0 * XN;
        for (int u = t; u < 2 * XN; u += 256) {
            const int r = u >> 9, j = u & (XN - 1);
            const int on = (ab[u] != 0) | (j == i0 + r);
            emf[j * 2 + r] = on ? eb[u] : 0.f;
            adf[j * 2 + r] = on ? 0.f : XMASK;
        }
        const float4* wu4 = (const float4*)Wu;
        const float4* wt4 = (const float4*)Wtm;
        ((float4*)wush)[t]        = wu4[t];
        ((float4*)wush)[t + 256]  = wu4[t + 256];
        ((float4*)wtmsh)[t]       = wt4[t];
        ((float4*)wtmsh)[t + 256] = wt4[t + 256];
        if (t < 192) wdsh[t] = Wd[t];
        if (t < 64)  wpsh[t] = Wp[t];
        if (t < 64) { zsf[t] = z[row0 * 32 + t]; a1sf[t] = A1[row0 * 32 + t]; }
    }
    __syncthreads();

    // ---- phase 1: j-scan, wide load groups ----
    const int c = t >> 5, l = t & 31;
    const float* Bp = B1 + (size_t)b * XN * 32 + l;
    const int j0 = c * 64;
    float m0 = XNEG, m1 = XNEG;
#pragma unroll 16
    for (int k = 0; k < 64; ++k) {
        const int j = j0 + k;
        const float bv = Bp[(size_t)j * 32];
        m0 = fmaxf(m0, fmaf(emf[j * 2],     c1v, bv) + adf[j * 2]);
        m1 = fmaxf(m1, fmaf(emf[j * 2 + 1], c1v, bv) + adf[j * 2 + 1]);
    }
    red[0][c][l] = m0;
    red[1][c][l] = m1;
    __syncthreads();

    // ---- phase 2: combine partial maxes, agg ----
    if (t < 64) {
        const int r = t >> 5, ll = t & 31;
        float mm = red[r][0][ll];
        for (int cc = 1; cc < 8; ++cc) mm = fmaxf(mm, red[r][cc][ll]);
        ags[t] = a1sf[t] + mm;
    }
    __syncthreads();

    // ---- phase 3: new_h (all operands in LDS) ----
    if (t < 64) {
        const int r = t >> 5, ll = t & 31;
        float v = zsf[t];                                 // residual + z
        for (int k = 0; k < 32; ++k)
            v += zsf[r * 32 + k] * wush[k * 32 + ll]
               + ags[r * 32 + k] * wush[(32 + k) * 32 + ll];
        nhs[t] = v;
        o_newh[row0 * 32 + t] = v;
    }
    __syncthreads();

    // ---- phase 4: A2/B2, hp heads, new_x (concurrent thread groups) ----
    if (t < 64) {
        const int r = t >> 5, ll = t & 31;
        float a2 = 0.f, b2 = 0.f;
        for (int k = 0; k < 32; ++k) {
            const float nk = nhs[r * 32 + k];
            a2 += nk * wtmsh[k * 32 + ll];
            b2 += nk * wtmsh[(32 + k) * 32 + ll];
        }
        A2[row0 * 32 + t] = a2;
        B2[row0 * 32 + t] = b2;
    } else if (t >= 128 && t < 132) {
        const int r = (t - 128) >> 1, which = (t - 128) & 1;
        float p = 0.f;
        for (int k = 0; k < 32; ++k) p += nhs[r * 32 + k] * wpsh[which * 32 + k];
        (which ? hp2 : hp1)[row0 + r] = p;
    } else if (t >= 160 && t < 166) {
        const int idx = t - 160, r = idx / 3, d = idx % 3;
        float v = 0.f;
        for (int k = 0; k < 32; ++k)
            v += zsf[r * 32 + k] * wdsh[k * 3 + d]
               + nhs[r * 32 + k] * wdsh[(32 + k) * 3 + d];
        o_newx[(row0 + r) * 3 + d] = v;
    }
}

// ---- m3: termination scan + fused p-head + tau — 2 rows/block ----
__global__ __launch_bounds__(256) void ne2v_m3(
    const int* __restrict__ adj, const float* __restrict__ ef,
    const float* __restrict__ A2, const float* __restrict__ B2,
    const float* __restrict__ newh, const float* __restrict__ hp1,
    const float* __restrict__ hp2, const float* __restrict__ drv,
    float* __restrict__ o_p, float* __restrict__ tau_out)
{
    const int q = blockIdx.x;
    const int b = q >> 8;
    const int i0 = (q & 255) * 2;
    const int row0 = b * XN + i0;
    const int t = threadIdx.x;

    __shared__ float emf[2 * XN];
    __shared__ float adf[2 * XN];
    __shared__ float hp2s[XN];
    __shared__ float a2sf[64], nhsf[64], ss[64];
    __shared__ float red[2][8][33];

    // ---- phase 0: staging ----
    const float c2v = drv[32 + (t & 31)];
    const float cpv = drv[128];
    const float h1a = hp1[row0];
    const float h1b = hp1[row0 + 1];
    {
        const int*   ab = adj + (size_t)row0 * XN;
        const float* eb = ef  + (size_t)row0 * XN;
        for (int u = t; u < 2 * XN; u += 256) {
            const int r = u >> 9, j = u & (XN - 1);
            const int on = (ab[u] != 0) | (j == i0 + r);
            emf[j * 2 + r] = on ? eb[u] : 0.f;
            adf[j * 2 + r] = on ? 0.f : XMASK;
        }
        for (int u = t; u < XN; u += 256) hp2s[u] = hp2[b * XN + u];
        if (t < 64) { a2sf[t] = A2[row0 * 32 + t]; nhsf[t] = newh[row0 * 32 + t]; }
    }
    __syncthreads();

    // ---- phase 1: fused predecessor head (stores don't block the scan) ----
    {
        float* pr0 = o_p + (size_t)row0 * XN;
        float* pr1 = pr0 + XN;
        for (int j = t; j < XN; j += 256) {
            pr0[j] = xscrub(h1a + hp2s[j] + emf[j * 2]     * cpv + adf[j * 2]);
            pr1[j] = xscrub(h1b + hp2s[j] + emf[j * 2 + 1] * cpv + adf[j * 2 + 1]);
        }
    }

    // ---- phase 2: j-scan over B2 ----
    const int c = t >> 5, l = t & 31;
    const float* Bp = B2 + (size_t)b * XN * 32 + l;
    const int j0 = c * 64;
    float m0 = XNEG, m1 = XNEG;
#pragma unroll 16
    for (int k = 0; k < 64; ++k) {
        const int j = j0 + k;
        const float bv = Bp[(size_t)j * 32];
        m0 = fmaxf(m0, fmaf(emf[j * 2],     c2v, bv) + adf[j * 2]);
        m1 = fmaxf(m1, fmaf(emf[j * 2 + 1], c2v, bv) + adf[j * 2 + 1]);
    }
    red[0][c][l] = m0;
    red[1][c][l] = m1;
    __syncthreads();

    // ---- phase 3: tau contribution ----
    if (t < 64) {
        const int r = t >> 5, ll = t & 31;
        float mm = red[r][0][ll];
        for (int cc = 1; cc < 8; ++cc) mm = fmaxf(mm, red[r][cc][ll]);
        const float agg = a2sf[t] + mm;
        ss[t] = nhsf[t] * drv[64 + ll] + agg * drv[96 + ll];
    }
    __syncthreads();
    if (t < 64) {
        float s = ss[t];
        s += __shfl_down(s, 32);
        s += __shfl_down(s, 16);
        s += __shfl_down(s, 8);
        s += __shfl_down(s, 4);
        s += __shfl_down(s, 2);
        s += __shfl_down(s, 1);
        if (t == 0) atomicAdd(&tau_out[b], s * (1.0f / XN));
    }
}

extern "C" void kernel_launch(void* const* d_in, const int* in_sizes, int n_in,
                              void* d_out, int out_size, void* d_ws, size_t ws_size,
                              hipStream_t stream)
{
    const float* x   = (const float*)d_in[0];
    const float* h   = (const float*)d_in[1];
    const int*   adj = (const int*)  d_in[2];
    const float* ef  = (const float*)d_in[3];
    const float* Wn  = (const float*)d_in[4];
    const float* We  = (const float*)d_in[5];
    const float* Wm  = (const float*)d_in[6];
    const float* Wu  = (const float*)d_in[7];
    const float* Wtm = (const float*)d_in[8];
    const float* Wtu = (const float*)d_in[9];
    const float* Wd  = (const float*)d_in[10];
    const float* Wt  = (const float*)d_in[11];
    const float* Wp  = (const float*)d_in[12];

    float* out    = (float*)d_out;
    float* o_newx = out;                          // [4,512,3]   6144
    float* o_p    = out + 6144;                   // [4,512,512] 1048576
    float* o_tau  = out + 6144 + XB * XN * XN;    // [4,1]       4
    float* o_newh = o_tau + XB;                   // [4,512,32]  65536

    float* w = (float*)d_ws;
    const int RN = XB * XN * 32;                  // 65536
    float* z   = w;
    float* A1  = w + RN;
    float* B1  = w + 2 * RN;
    float* A2  = w + 3 * RN;
    float* B2  = w + 4 * RN;
    float* hp1 = w + 5 * RN;
    float* hp2 = w + 5 * RN + XB * XN;
    float* drv = w + 5 * RN + 2 * XB * XN;

    hipLaunchKernelGGL(ne2v_g0, dim3(1), dim3(64), 0, stream,
                       We, Wm, Wtm, Wtu, Wt, Wp, drv, o_tau);
    hipLaunchKernelGGL(ne2v_g1, dim3(XB * XN / 8), dim3(256), 0, stream,
                       x, h, Wn, Wm, z, A1, B1);
    hipLaunchKernelGGL(ne2v_m2, dim3(XB * XN / 2), dim3(256), 0, stream,
                       adj, ef, z, A1, B1, drv, Wu, Wd, Wtm, Wp,
                       A2, B2, hp1, hp2, o_newx, o_newh);
    hipLaunchKernelGGL(ne2v_m3, dim3(XB * XN / 2), dim3(256), 0, stream,
                       adj, ef, A2, B2, o_newh, hp1, hp2, drv, o_p, o_tau);
}